// Round 3
// baseline (495.193 us; speedup 1.0000x reference)
//
#include <hip/hip_runtime.h>
#include <hip/hip_bf16.h>

// EPMoE: E=8, K=2, D=1024, F=2048, T=2048, ROWS=4096.
// Fast path: route -> convT_all (fp32 W -> bf16 W^T, LDS-free, 1 dispatch) ->
// gather (x->xs bf16) -> gemm1 (global_load_lds + XOR bank swizzle, SwiGLU) ->
// gemm2 (y plain stores, no atomics) -> combine (weighted unpermute).
// LDS swizzle: tile [R][64] bf16, row = 128B = exactly 32 banks; physical
// 16B-chunk j of row m holds global chunk j^(m&7) (source-addr swizzle keeps
// global_load_lds's lane-contiguous dst). Frag reads then spread 8 lanes per
// 4-bank group = b128 floor instead of 16 (half banks idle).

#define D_DIM 1024
#define F_DIM 2048
#define ROWS 4096
#define MAXTILE 40
#define LDK 72   // fallback-path LDS k-stride

using f32x4 = __attribute__((ext_vector_type(4))) float;
using s16x8 = __attribute__((ext_vector_type(8))) short;

__device__ __forceinline__ unsigned pack_trunc(float lo, float hi) {
  return (__float_as_uint(lo) >> 16) | (__float_as_uint(hi) & 0xffff0000u);
}
__device__ __forceinline__ unsigned short bf_rn(float f) {
  unsigned u = __float_as_uint(f);
  u += 0x7fffu + ((u >> 16) & 1u);
  return (unsigned short)(u >> 16);
}
__device__ __forceinline__ unsigned pack_rn(float lo, float hi) {
  return (unsigned)bf_rn(lo) | ((unsigned)bf_rn(hi) << 16);
}

typedef const __attribute__((address_space(1))) void* gp_t;
typedef __attribute__((address_space(3))) void* lp_t;
__device__ __forceinline__ void load16(const void* g, void* l) {
  __builtin_amdgcn_global_load_lds((gp_t)g, (lp_t)l, 16, 0, 0);
}

// ---------------- routing: stable counting sort by expert ----------------
__global__ __launch_bounds__(512) void route_kernel(const int* __restrict__ ids,
                                                    int* __restrict__ sorted_flat,
                                                    int* __restrict__ unsort,
                                                    int* __restrict__ tile_meta) {
  __shared__ int cnt[8];
  __shared__ int off[9];
  const int tid = threadIdx.x;
  const int w = tid >> 6, lane = tid & 63;
  int c = 0;
  for (int base = 0; base < ROWS; base += 64) {
    int e = ids[base + lane];
    c += __popcll(__ballot(e == w));
  }
  if (lane == 0) cnt[w] = c;
  __syncthreads();
  if (tid == 0) {
    int o = 0;
    for (int e = 0; e < 8; e++) { off[e] = o; o += cnt[e]; }
    off[8] = o;
    int nT = 0;
    for (int e = 0; e < 8; e++) {
      for (int r0 = off[e]; r0 < off[e + 1]; r0 += 128) {
        tile_meta[1 + 3 * nT] = r0;
        tile_meta[2 + 3 * nT] = off[e + 1];
        tile_meta[3 + 3 * nT] = e;
        nT++;
      }
    }
    tile_meta[0] = nT;
  }
  __syncthreads();
  int pos = off[w];
  const unsigned long long below = (1ull << lane) - 1ull;
  for (int base = 0; base < ROWS; base += 64) {
    int e = ids[base + lane];
    unsigned long long m = __ballot(e == w);
    if (e == w) {
      int p = pos + __popcll(m & below);
      sorted_flat[p] = base + lane;
      unsort[base + lane] = p;
    }
    pos += __popcll(m);
  }
}

__global__ void zero_kernel(float4* __restrict__ p, int n4) {
  int i = blockIdx.x * blockDim.x + threadIdx.x;
  if (i < n4) p[i] = float4{0.f, 0.f, 0.f, 0.f};
}

// ------- convT_all: 3 weight tensors fp32 [E][Kd][Nd] -> bf16 [E][Nd][Kd] -------
// LDS-free: each thread reads 8 float4 (128B, 8 k-rows x 4 n), packs k-pairs,
// writes 4 uint4 (fully vectorized). One dispatch for all 24 expert-tensors.
__global__ __launch_bounds__(256) void convT_all(
    const float* __restrict__ wi0, const float* __restrict__ wi1,
    const float* __restrict__ wo, unsigned short* __restrict__ w0T,
    unsigned short* __restrict__ w1T, unsigned short* __restrict__ woT) {
  const int z = blockIdx.y;            // 0..23
  const int which = z >> 3, e = z & 7;
  const float* S;
  unsigned short* Dp;
  int Kd, Nd, kb_bits;
  if (which == 0)      { S = wi0; Dp = w0T; Kd = D_DIM; Nd = F_DIM; kb_bits = 3; }
  else if (which == 1) { S = wi1; Dp = w1T; Kd = D_DIM; Nd = F_DIM; kb_bits = 3; }
  else                 { S = wo;  Dp = woT; Kd = F_DIM; Nd = D_DIM; kb_bits = 4; }
  S  += (size_t)e * Kd * Nd;
  Dp += (size_t)e * Kd * Nd;
  const int bx = blockIdx.x;           // 0..255  (Kd/128 * Nd/64 == 256 for both)
  const int k = (bx & ((1 << kb_bits) - 1)) * 128 + (threadIdx.x >> 4) * 8;
  const int n = (bx >> kb_bits) * 64 + (threadIdx.x & 15) * 4;
  float4 v[8];
#pragma unroll
  for (int i = 0; i < 8; i++)
    v[i] = *(const float4*)(S + (size_t)(k + i) * Nd + n);
  const float* fv = (const float*)v;
#pragma unroll
  for (int j = 0; j < 4; j++) {
    uint4 o;
    o.x = pack_rn(fv[0 * 4 + j], fv[1 * 4 + j]);
    o.y = pack_rn(fv[2 * 4 + j], fv[3 * 4 + j]);
    o.z = pack_rn(fv[4 * 4 + j], fv[5 * 4 + j]);
    o.w = pack_rn(fv[6 * 4 + j], fv[7 * 4 + j]);
    *(uint4*)(Dp + (size_t)(n + j) * Kd + k) = o;
  }
}

// ---------------- gather: x fp32 -> x_sorted bf16 ----------------
__global__ __launch_bounds__(256) void gather_kernel(const float* __restrict__ x,
                                                     const int* __restrict__ sorted_flat,
                                                     unsigned short* __restrict__ xs) {
  const int r = blockIdx.x;
  const int tok = sorted_flat[r] >> 1;
  const float4 v = *(const float4*)(x + (size_t)tok * D_DIM + threadIdx.x * 4);
  *(uint2*)(xs + (size_t)r * D_DIM + threadIdx.x * 4) =
      make_uint2(pack_rn(v.x, v.y), pack_rn(v.z, v.w));
}

// swizzled frag address: physical chunk = logical_chunk ^ (row&7)
__device__ __forceinline__ int sw(int row, int chunk) {
  return row * 64 + ((chunk ^ (row & 7)) << 3);
}

// ---------------- GEMM1: xs @ (w0T,w1T) -> h = silu(g0)*g1 ----------------
__global__ __launch_bounds__(256, 3) void gemm1_kernel(
    const unsigned short* __restrict__ xs, const unsigned short* __restrict__ w0T,
    const unsigned short* __restrict__ w1T, const int* __restrict__ tile_meta,
    unsigned short* __restrict__ h) {
  __shared__ unsigned short As[128 * 64];
  __shared__ unsigned short B0s[128 * 64];
  __shared__ unsigned short B1s[128 * 64];
  const int tile = blockIdx.x;
  if (tile >= tile_meta[0]) return;
  const int row0 = tile_meta[1 + 3 * tile];
  const int rowEnd = tile_meta[2 + 3 * tile];
  const int e = tile_meta[3 + 3 * tile];
  const int n0 = blockIdx.y * 128;
  const unsigned short* W0 = w0T + ((size_t)e * F_DIM + n0) * D_DIM;
  const unsigned short* W1 = w1T + ((size_t)e * F_DIM + n0) * D_DIM;

  const int tid = threadIdx.x;
  const int lane = tid & 63, wv = tid >> 6;
  const int wm = (wv & 1) * 64, wn = (wv >> 1) * 64;
  const int lm = lane & 15, lq = lane >> 4;
  const int srow = lane >> 3;                       // staging row-in-chunk
  const int skk = ((lane & 7) ^ srow) << 3;         // swizzled source elem off

  f32x4 acc0[4][4], acc1[4][4];
#pragma unroll
  for (int i = 0; i < 4; i++)
#pragma unroll
    for (int j = 0; j < 4; j++) { acc0[i][j] = 0.f; acc1[i][j] = 0.f; }

  for (int k0 = 0; k0 < D_DIM; k0 += 64) {
    __syncthreads();
#pragma unroll
    for (int r = 0; r < 4; r++) {
      const int c = r * 4 + wv;          // 8-row chunk id, wave-uniform
      const int m = c * 8 + srow;
      int mc = row0 + m; if (mc > ROWS - 1) mc = ROWS - 1;
      load16(xs + (size_t)mc * D_DIM + k0 + skk, (char*)As + c * 1024);
      load16(W0 + (size_t)m * D_DIM + k0 + skk, (char*)B0s + c * 1024);
      load16(W1 + (size_t)m * D_DIM + k0 + skk, (char*)B1s + c * 1024);
    }
    __syncthreads();
#pragma unroll
    for (int ks = 0; ks < 64; ks += 32) {
      const int cb = (ks >> 3) + lq;
      s16x8 af[4], b0[4], b1[4];
#pragma unroll
      for (int t = 0; t < 4; t++) {
        af[t] = *(const s16x8*)&As[sw(wm + t * 16 + lm, cb)];
        b0[t] = *(const s16x8*)&B0s[sw(wn + t * 16 + lm, cb)];
        b1[t] = *(const s16x8*)&B1s[sw(wn + t * 16 + lm, cb)];
      }
#pragma unroll
      for (int im = 0; im < 4; im++)
#pragma unroll
        for (int in = 0; in < 4; in++) {
          acc0[im][in] = __builtin_amdgcn_mfma_f32_16x16x32_bf16(
              af[im], b0[in], acc0[im][in], 0, 0, 0);
          acc1[im][in] = __builtin_amdgcn_mfma_f32_16x16x32_bf16(
              af[im], b1[in], acc1[im][in], 0, 0, 0);
        }
    }
  }
#pragma unroll
  for (int im = 0; im < 4; im++) {
    int gmB = row0 + wm + im * 16 + lq * 4;
#pragma unroll
    for (int in = 0; in < 4; in++) {
      int gn = n0 + wn + in * 16 + lm;
#pragma unroll
      for (int r = 0; r < 4; r++) {
        int gm = gmB + r;
        if (gm < rowEnd) {
          float g = acc0[im][in][r];
          float s = g / (1.f + __expf(-g));
          h[(size_t)gm * F_DIM + gn] = bf_rn(s * acc1[im][in][r]);
        }
      }
    }
  }
}

// ---------------- GEMM2: h @ woT -> y (plain stores, 128x64 tiles) ----------------
__global__ __launch_bounds__(256, 4) void gemm2_kernel(
    const unsigned short* __restrict__ h, const unsigned short* __restrict__ woT,
    const int* __restrict__ tile_meta, float* __restrict__ y) {
  __shared__ unsigned short As[128 * 64];
  __shared__ unsigned short Bs[64 * 64];
  const int tile = blockIdx.x;
  if (tile >= tile_meta[0]) return;
  const int row0 = tile_meta[1 + 3 * tile];
  const int rowEnd = tile_meta[2 + 3 * tile];
  const int e = tile_meta[3 + 3 * tile];
  const int n0 = blockIdx.y * 64;
  const unsigned short* W = woT + ((size_t)e * D_DIM + n0) * F_DIM;

  const int tid = threadIdx.x;
  const int lane = tid & 63, wv = tid >> 6;
  const int wm = (wv & 1) * 64, wn = (wv >> 1) * 32;
  const int lm = lane & 15, lq = lane >> 4;
  const int srow = lane >> 3;
  const int skk = ((lane & 7) ^ srow) << 3;

  f32x4 acc[4][2];
#pragma unroll
  for (int i = 0; i < 4; i++)
#pragma unroll
    for (int j = 0; j < 2; j++) acc[i][j] = 0.f;

  for (int k0 = 0; k0 < F_DIM; k0 += 64) {
    __syncthreads();
#pragma unroll
    for (int r = 0; r < 4; r++) {
      const int c = r * 4 + wv;
      const int m = c * 8 + srow;
      int mc = row0 + m; if (mc > ROWS - 1) mc = ROWS - 1;
      load16(h + (size_t)mc * F_DIM + k0 + skk, (char*)As + c * 1024);
    }
#pragma unroll
    for (int r = 0; r < 2; r++) {
      const int c = r * 4 + wv;
      const int m = c * 8 + srow;
      load16(W + (size_t)m * F_DIM + k0 + skk, (char*)Bs + c * 1024);
    }
    __syncthreads();
#pragma unroll
    for (int ks = 0; ks < 64; ks += 32) {
      const int cb = (ks >> 3) + lq;
      s16x8 af[4], bf[2];
#pragma unroll
      for (int t = 0; t < 4; t++)
        af[t] = *(const s16x8*)&As[sw(wm + t * 16 + lm, cb)];
#pragma unroll
      for (int t = 0; t < 2; t++)
        bf[t] = *(const s16x8*)&Bs[sw(wn + t * 16 + lm, cb)];
#pragma unroll
      for (int im = 0; im < 4; im++)
#pragma unroll
        for (int in = 0; in < 2; in++)
          acc[im][in] = __builtin_amdgcn_mfma_f32_16x16x32_bf16(
              af[im], bf[in], acc[im][in], 0, 0, 0);
    }
  }
#pragma unroll
  for (int im = 0; im < 4; im++) {
    int gmB = row0 + wm + im * 16 + lq * 4;
#pragma unroll
    for (int in = 0; in < 2; in++) {
      int gn = n0 + wn + in * 16 + lm;
#pragma unroll
      for (int r = 0; r < 4; r++) {
        int gm = gmB + r;
        if (gm < rowEnd) y[(size_t)gm * D_DIM + gn] = acc[im][in][r];
      }
    }
  }
}

// ---------------- combine: out[t] = tw0*y[unsort[2t]] + tw1*y[unsort[2t+1]] ----
__global__ __launch_bounds__(256) void combine_kernel(const float* __restrict__ y,
                                                      const float* __restrict__ tw,
                                                      const int* __restrict__ unsort,
                                                      float* __restrict__ out) {
  const int tkn = blockIdx.x;
  const int r0 = unsort[2 * tkn], r1 = unsort[2 * tkn + 1];
  const float w0 = tw[2 * tkn], w1 = tw[2 * tkn + 1];
  const int c = threadIdx.x * 4;
  float4 a = *(const float4*)(y + (size_t)r0 * D_DIM + c);
  float4 b = *(const float4*)(y + (size_t)r1 * D_DIM + c);
  float4 o = {w0 * a.x + w1 * b.x, w0 * a.y + w1 * b.y,
              w0 * a.z + w1 * b.z, w0 * a.w + w1 * b.w};
  *(float4*)(out + (size_t)tkn * D_DIM + c) = o;
}

// ================= fallback (round-0) kernels, small-ws path =================
__device__ __forceinline__ void stage_bt(const float* __restrict__ Wt, int ldw,
                                         unsigned short* Bs, int tid) {
#pragma unroll
  for (int it = 0; it < 4; it++) {
    const int kp = (tid & 7) + it * 8;
    const int nq = tid >> 3;
    const float* p = Wt + (size_t)(2 * kp) * ldw + nq * 4;
    const float4 va = *(const float4*)p;
    const float4 vb = *(const float4*)(p + ldw);
    unsigned short* b = Bs + (nq * 4) * LDK + 2 * kp;
    *(unsigned*)(b)           = pack_trunc(va.x, vb.x);
    *(unsigned*)(b + LDK)     = pack_trunc(va.y, vb.y);
    *(unsigned*)(b + 2 * LDK) = pack_trunc(va.z, vb.z);
    *(unsigned*)(b + 3 * LDK) = pack_trunc(va.w, vb.w);
  }
}

__global__ __launch_bounds__(256, 2) void gemm1_fb(
    const float* __restrict__ x, const float* __restrict__ wi0,
    const float* __restrict__ wi1, const int* __restrict__ sorted_flat,
    const int* __restrict__ tile_meta, unsigned short* __restrict__ h) {
  __shared__ unsigned short As[128 * LDK];
  __shared__ unsigned short B0s[128 * LDK];
  __shared__ unsigned short B1s[128 * LDK];
  __shared__ int tok[128];
  const int tile = blockIdx.x;
  if (tile >= tile_meta[0]) return;
  const int row0 = tile_meta[1 + 3 * tile];
  const int rowEnd = tile_meta[2 + 3 * tile];
  const int e = tile_meta[3 + 3 * tile];
  const int n0 = blockIdx.y * 128;
  const float* W0 = wi0 + (size_t)e * D_DIM * F_DIM;
  const float* W1 = wi1 + (size_t)e * D_DIM * F_DIM;
  const int tid = threadIdx.x;
  if (tid < 128) {
    int r = row0 + tid; if (r > ROWS - 1) r = ROWS - 1;
    tok[tid] = sorted_flat[r] >> 1;
  }
  f32x4 acc0[4][4], acc1[4][4];
#pragma unroll
  for (int i = 0; i < 4; i++)
#pragma unroll
    for (int j = 0; j < 4; j++) { acc0[i][j] = 0.f; acc1[i][j] = 0.f; }
  const int lane = tid & 63, wv = tid >> 6;
  const int wm = (wv & 1) * 64, wn = (wv >> 1) * 64;
  const int lm = lane & 15, lq = lane >> 4;
  for (int k0 = 0; k0 < D_DIM; k0 += 64) {
    __syncthreads();
#pragma unroll
    for (int i = 0; i < 8; i++) {
      int idx = tid + i * 256;
      int m = idx >> 4, kq = idx & 15;
      float4 v = *(const float4*)(x + (size_t)tok[m] * D_DIM + k0 + kq * 4);
      *(uint2*)&As[m * LDK + kq * 4] =
          make_uint2(pack_trunc(v.x, v.y), pack_trunc(v.z, v.w));
    }
    stage_bt(W0 + (size_t)k0 * F_DIM + n0, F_DIM, B0s, tid);
    stage_bt(W1 + (size_t)k0 * F_DIM + n0, F_DIM, B1s, tid);
    __syncthreads();
#pragma unroll
    for (int ks = 0; ks < 64; ks += 32) {
      s16x8 af[4], b0[4], b1[4];
#pragma unroll
      for (int t = 0; t < 4; t++) {
        af[t] = *(const s16x8*)&As[(wm + t * 16 + lm) * LDK + ks + lq * 8];
        b0[t] = *(const s16x8*)&B0s[(wn + t * 16 + lm) * LDK + ks + lq * 8];
        b1[t] = *(const s16x8*)&B1s[(wn + t * 16 + lm) * LDK + ks + lq * 8];
      }
#pragma unroll
      for (int im = 0; im < 4; im++)
#pragma unroll
        for (int in = 0; in < 4; in++) {
          acc0[im][in] = __builtin_amdgcn_mfma_f32_16x16x32_bf16(
              af[im], b0[in], acc0[im][in], 0, 0, 0);
          acc1[im][in] = __builtin_amdgcn_mfma_f32_16x16x32_bf16(
              af[im], b1[in], acc1[im][in], 0, 0, 0);
        }
    }
  }
#pragma unroll
  for (int im = 0; im < 4; im++) {
    int gmB = row0 + wm + im * 16 + lq * 4;
#pragma unroll
    for (int in = 0; in < 4; in++) {
      int gn = n0 + wn + in * 16 + lm;
#pragma unroll
      for (int r = 0; r < 4; r++) {
        int gm = gmB + r;
        if (gm < rowEnd) {
          float g = acc0[im][in][r];
          float s = g / (1.f + __expf(-g));
          h[(size_t)gm * F_DIM + gn] = bf_rn(s * acc1[im][in][r]);
        }
      }
    }
  }
}

__global__ __launch_bounds__(256, 3) void gemm2_fb(
    const unsigned short* __restrict__ h, const float* __restrict__ wo,
    const float* __restrict__ tw, const int* __restrict__ sorted_flat,
    const int* __restrict__ tile_meta, float* __restrict__ out) {
  __shared__ unsigned short As[128 * LDK];
  __shared__ unsigned short Bs[128 * LDK];
  __shared__ int sTok[128];
  __shared__ float sWgt[128];
  const int tile = blockIdx.x;
  if (tile >= tile_meta[0]) return;
  const int row0 = tile_meta[1 + 3 * tile];
  const int rowEnd = tile_meta[2 + 3 * tile];
  const int e = tile_meta[3 + 3 * tile];
  const int n0 = blockIdx.y * 128;
  const float* W = wo + (size_t)e * F_DIM * D_DIM;
  const int tid = threadIdx.x;
  if (tid < 128) {
    int r = row0 + tid; if (r > ROWS - 1) r = ROWS - 1;
    int fl = sorted_flat[r];
    sTok[tid] = fl >> 1;
    sWgt[tid] = tw[fl];
  }
  f32x4 acc[4][4];
#pragma unroll
  for (int i = 0; i < 4; i++)
#pragma unroll
    for (int j = 0; j < 4; j++) acc[i][j] = 0.f;
  const int lane = tid & 63, wv = tid >> 6;
  const int wm = (wv & 1) * 64, wn = (wv >> 1) * 64;
  const int lm = lane & 15, lq = lane >> 4;
  for (int k0 = 0; k0 < F_DIM; k0 += 64) {
    __syncthreads();
#pragma unroll
    for (int i = 0; i < 8; i++) {
      int idx = tid + i * 256;
      int m = idx >> 4, kq = idx & 15;
      int gm = row0 + m; if (gm > ROWS - 1) gm = ROWS - 1;
      *(uint2*)&As[m * LDK + kq * 4] =
          *(const uint2*)(h + (size_t)gm * F_DIM + k0 + kq * 4);
    }
    stage_bt(W + (size_t)k0 * D_DIM + n0, D_DIM, Bs, tid);
    __syncthreads();
#pragma unroll
    for (int ks = 0; ks < 64; ks += 32) {
      s16x8 af[4], bf[4];
#pragma unroll
      for (int t = 0; t < 4; t++) {
        af[t] = *(const s16x8*)&As[(wm + t * 16 + lm) * LDK + ks + lq * 8];
        bf[t] = *(const s16x8*)&Bs[(wn + t * 16 + lm) * LDK + ks + lq * 8];
      }
#pragma unroll
      for (int im = 0; im < 4; im++)
#pragma unroll
        for (int in = 0; in < 4; in++)
          acc[im][in] = __builtin_amdgcn_mfma_f32_16x16x32_bf16(
              af[im], bf[in], acc[im][in], 0, 0, 0);
    }
  }
#pragma unroll
  for (int im = 0; im < 4; im++) {
    int lrB = wm + im * 16 + lq * 4;
#pragma unroll
    for (int in = 0; in < 4; in++) {
      int gn = n0 + wn + in * 16 + lm;
#pragma unroll
      for (int r = 0; r < 4; r++) {
        int lr = lrB + r;
        int gm = row0 + lr;
        if (gm < rowEnd)
          atomicAdd(out + (size_t)sTok[lr] * D_DIM + gn, sWgt[lr] * acc[im][in][r]);
      }
    }
  }
}

extern "C" void kernel_launch(void* const* d_in, const int* in_sizes, int n_in,
                              void* d_out, int out_size, void* d_ws, size_t ws_size,
                              hipStream_t stream) {
  const float* x   = (const float*)d_in[0];
  const float* tw  = (const float*)d_in[1];
  const int*   ids = (const int*)d_in[2];
  const float* wi0 = (const float*)d_in[3];
  const float* wi1 = (const float*)d_in[4];
  const float* wo  = (const float*)d_in[5];
  float* out = (float*)d_out;

  int* tile_meta = (int*)d_ws;            // 256 ints
  int* sorted_flat = tile_meta + 256;     // 4096 ints
  int* unsort = sorted_flat + ROWS;       // 4096 ints (ends < 64KB)

  const size_t MB = 1024 * 1024;
  const size_t XS_OFF = 64 * 1024;
  const size_t H_OFF  = XS_OFF + 8 * MB;
  const size_t W0_OFF = H_OFF + 16 * MB;   // y (16MB fp32) reuses this after gemm1
  const size_t W1_OFF = W0_OFF + 32 * MB;
  const size_t WO_OFF = W1_OFF + 32 * MB;
  const size_t NEED   = WO_OFF + 32 * MB;  // ~120.06 MB

  route_kernel<<<1, 512, 0, stream>>>(ids, sorted_flat, unsort, tile_meta);
  if (ws_size >= NEED) {
    unsigned short* xs  = (unsigned short*)((char*)d_ws + XS_OFF);
    unsigned short* h   = (unsigned short*)((char*)d_ws + H_OFF);
    unsigned short* w0T = (unsigned short*)((char*)d_ws + W0_OFF);
    unsigned short* w1T = (unsigned short*)((char*)d_ws + W1_OFF);
    unsigned short* woT = (unsigned short*)((char*)d_ws + WO_OFF);
    float* y = (float*)((char*)d_ws + W0_OFF);   // w0T dead after gemm1

    convT_all<<<dim3(256, 24), 256, 0, stream>>>(wi0, wi1, wo, w0T, w1T, woT);
    gather_kernel<<<ROWS, 256, 0, stream>>>(x, sorted_flat, xs);
    gemm1_kernel<<<dim3(MAXTILE, F_DIM / 128), 256, 0, stream>>>(xs, w0T, w1T,
                                                                 tile_meta, h);
    gemm2_kernel<<<dim3(MAXTILE, D_DIM / 64), 256, 0, stream>>>(h, woT,
                                                                tile_meta, y);
    combine_kernel<<<ROWS / 2, 256, 0, stream>>>(y, tw, unsort, out);
  } else {
    unsigned short* h = (unsigned short*)((char*)d_ws + XS_OFF);
    zero_kernel<<<(out_size / 4 + 255) / 256, 256, 0, stream>>>((float4*)out,
                                                                out_size / 4);
    gemm1_fb<<<dim3(MAXTILE, F_DIM / 128), 256, 0, stream>>>(x, wi0, wi1,
                                                             sorted_flat,
                                                             tile_meta, h);
    gemm2_fb<<<dim3(MAXTILE, D_DIM / 128), 256, 0, stream>>>(h, wo, tw,
                                                             sorted_flat,
                                                             tile_meta, out);
  }
}

// Round 4
// 342.468 us; speedup vs baseline: 1.4460x; 1.4460x over previous
//
#include <hip/hip_runtime.h>
#include <hip/hip_bf16.h>

// EPMoE: E=8, K=2, D=1024, F=2048, T=2048, ROWS=4096.
// Fast path: route -> convT_lds (fp32 W -> bf16 W^T, LDS transpose, coalesced
// both sides, 1 dispatch) -> gather (x->xs bf16) -> gemm1 (global_load_lds +
// XOR bank swizzle, SwiGLU) -> gemm2 (plain y stores) -> combine.
// gemm1 MUST stay __launch_bounds__(256,2): acc = 128 AGPRs + ~120 VGPRs; at
// 3 waves/EU the unified budget (~170) forces accumulator spill (R3: 391MB
// scratch writes, 230us). LDS swizzle: [R][64] bf16 tile rows = 128B = 32
// banks; physical 16B chunk j of row m holds logical chunk j^(m&7) (swizzle
// applied on global source addr; global_load_lds dst stays lane-contiguous).

#define D_DIM 1024
#define F_DIM 2048
#define ROWS 4096
#define MAXTILE 40
#define LDK 72   // fallback-path LDS k-stride

using f32x4 = __attribute__((ext_vector_type(4))) float;
using s16x8 = __attribute__((ext_vector_type(8))) short;

__device__ __forceinline__ unsigned pack_trunc(float lo, float hi) {
  return (__float_as_uint(lo) >> 16) | (__float_as_uint(hi) & 0xffff0000u);
}
__device__ __forceinline__ unsigned short bf_rn(float f) {
  unsigned u = __float_as_uint(f);
  u += 0x7fffu + ((u >> 16) & 1u);
  return (unsigned short)(u >> 16);
}
__device__ __forceinline__ unsigned pack_rn(float lo, float hi) {
  return (unsigned)bf_rn(lo) | ((unsigned)bf_rn(hi) << 16);
}

typedef const __attribute__((address_space(1))) void* gp_t;
typedef __attribute__((address_space(3))) void* lp_t;
__device__ __forceinline__ void load16(const void* g, void* l) {
  __builtin_amdgcn_global_load_lds((gp_t)g, (lp_t)l, 16, 0, 0);
}

// ---------------- routing: stable counting sort by expert ----------------
__global__ __launch_bounds__(512) void route_kernel(const int* __restrict__ ids,
                                                    int* __restrict__ sorted_flat,
                                                    int* __restrict__ unsort,
                                                    int* __restrict__ tile_meta) {
  __shared__ int cnt[8];
  __shared__ int off[9];
  const int tid = threadIdx.x;
  const int w = tid >> 6, lane = tid & 63;
  int c = 0;
  for (int base = 0; base < ROWS; base += 64) {
    int e = ids[base + lane];
    c += __popcll(__ballot(e == w));
  }
  if (lane == 0) cnt[w] = c;
  __syncthreads();
  if (tid == 0) {
    int o = 0;
    for (int e = 0; e < 8; e++) { off[e] = o; o += cnt[e]; }
    off[8] = o;
    int nT = 0;
    for (int e = 0; e < 8; e++) {
      for (int r0 = off[e]; r0 < off[e + 1]; r0 += 128) {
        tile_meta[1 + 3 * nT] = r0;
        tile_meta[2 + 3 * nT] = off[e + 1];
        tile_meta[3 + 3 * nT] = e;
        nT++;
      }
    }
    tile_meta[0] = nT;
  }
  __syncthreads();
  int pos = off[w];
  const unsigned long long below = (1ull << lane) - 1ull;
  for (int base = 0; base < ROWS; base += 64) {
    int e = ids[base + lane];
    unsigned long long m = __ballot(e == w);
    if (e == w) {
      int p = pos + __popcll(m & below);
      sorted_flat[p] = base + lane;
      unsort[base + lane] = p;
    }
    pos += __popcll(m);
  }
}

__global__ void zero_kernel(float4* __restrict__ p, int n4) {
  int i = blockIdx.x * blockDim.x + threadIdx.x;
  if (i < n4) p[i] = float4{0.f, 0.f, 0.f, 0.f};
}

// ------- convT_lds: 3 weight tensors fp32 [E][Kd][Nd] -> bf16 [E][Nd][Kd] -------
// 64x64 tile per block. Coalesced 256B-segment reads (2 k-rows x float4/thread
// x2), VALU k-pair packing, LDS [n][33 uints] (2-way = free conflicts both
// sides), coalesced 128B/row writes (full 64B sectors). HBM-bound: 480MB.
__global__ __launch_bounds__(256) void convT_lds(
    const float* __restrict__ wi0, const float* __restrict__ wi1,
    const float* __restrict__ wo, unsigned short* __restrict__ w0T,
    unsigned short* __restrict__ w1T, unsigned short* __restrict__ woT) {
  __shared__ unsigned t[64 * 33];  // [n][kpair]
  const int z = blockIdx.y;        // 0..23
  const int which = z >> 3, e = z & 7;
  const float* S;
  unsigned short* Dp;
  int Kd, Nd, nbits;
  if (which == 0)      { S = wi0; Dp = w0T; Kd = D_DIM; Nd = F_DIM; nbits = 5; }
  else if (which == 1) { S = wi1; Dp = w1T; Kd = D_DIM; Nd = F_DIM; nbits = 5; }
  else                 { S = wo;  Dp = woT; Kd = F_DIM; Nd = D_DIM; nbits = 4; }
  S  += (size_t)e * Kd * Nd;
  Dp += (size_t)e * Kd * Nd;
  const int n0 = (blockIdx.x & ((1 << nbits) - 1)) * 64;
  const int k0 = (blockIdx.x >> nbits) * 64;
  const int tid = threadIdx.x;
  const int nb = (tid & 15) * 4;
#pragma unroll
  for (int i = 0; i < 2; i++) {
    const int kp = (tid >> 4) + i * 16;  // k-pair 0..31
    const float* p = S + (size_t)(k0 + 2 * kp) * Nd + n0 + nb;
    float4 v0 = *(const float4*)p;
    float4 v1 = *(const float4*)(p + Nd);
    t[(nb + 0) * 33 + kp] = pack_rn(v0.x, v1.x);
    t[(nb + 1) * 33 + kp] = pack_rn(v0.y, v1.y);
    t[(nb + 2) * 33 + kp] = pack_rn(v0.z, v1.z);
    t[(nb + 3) * 33 + kp] = pack_rn(v0.w, v1.w);
  }
  __syncthreads();
  const int co = (tid & 7) * 4;        // uint offset within row
#pragma unroll
  for (int i = 0; i < 2; i++) {
    const int n = (tid >> 3) + i * 32;
    const unsigned* q = &t[n * 33 + co];
    uint4 o = make_uint4(q[0], q[1], q[2], q[3]);
    *(uint4*)(Dp + (size_t)(n0 + n) * Kd + k0 + co * 2) = o;
  }
}

// ---------------- gather: x fp32 -> x_sorted bf16 ----------------
__global__ __launch_bounds__(256) void gather_kernel(const float* __restrict__ x,
                                                     const int* __restrict__ sorted_flat,
                                                     unsigned short* __restrict__ xs) {
  const int r = blockIdx.x;
  const int tok = sorted_flat[r] >> 1;
  const float4 v = *(const float4*)(x + (size_t)tok * D_DIM + threadIdx.x * 4);
  *(uint2*)(xs + (size_t)r * D_DIM + threadIdx.x * 4) =
      make_uint2(pack_rn(v.x, v.y), pack_rn(v.z, v.w));
}

// swizzled frag address: physical chunk = logical_chunk ^ (row&7)
__device__ __forceinline__ int sw(int row, int chunk) {
  return row * 64 + ((chunk ^ (row & 7)) << 3);
}

// ---------------- GEMM1: xs @ (w0T,w1T) -> h = silu(g0)*g1 ----------------
__global__ __launch_bounds__(256, 2) void gemm1_kernel(
    const unsigned short* __restrict__ xs, const unsigned short* __restrict__ w0T,
    const unsigned short* __restrict__ w1T, const int* __restrict__ tile_meta,
    unsigned short* __restrict__ h) {
  __shared__ unsigned short As[128 * 64];
  __shared__ unsigned short B0s[128 * 64];
  __shared__ unsigned short B1s[128 * 64];
  const int tile = blockIdx.x;
  if (tile >= tile_meta[0]) return;
  const int row0 = tile_meta[1 + 3 * tile];
  const int rowEnd = tile_meta[2 + 3 * tile];
  const int e = tile_meta[3 + 3 * tile];
  const int n0 = blockIdx.y * 128;
  const unsigned short* W0 = w0T + ((size_t)e * F_DIM + n0) * D_DIM;
  const unsigned short* W1 = w1T + ((size_t)e * F_DIM + n0) * D_DIM;

  const int tid = threadIdx.x;
  const int lane = tid & 63, wv = tid >> 6;
  const int wm = (wv & 1) * 64, wn = (wv >> 1) * 64;
  const int lm = lane & 15, lq = lane >> 4;
  const int srow = lane >> 3;                       // staging row-in-chunk
  const int skk = ((lane & 7) ^ srow) << 3;         // swizzled source elem off

  f32x4 acc0[4][4], acc1[4][4];
#pragma unroll
  for (int i = 0; i < 4; i++)
#pragma unroll
    for (int j = 0; j < 4; j++) { acc0[i][j] = 0.f; acc1[i][j] = 0.f; }

  for (int k0 = 0; k0 < D_DIM; k0 += 64) {
    __syncthreads();
#pragma unroll
    for (int r = 0; r < 4; r++) {
      const int c = r * 4 + wv;          // 8-row chunk id, wave-uniform
      const int m = c * 8 + srow;
      int mc = row0 + m; if (mc > ROWS - 1) mc = ROWS - 1;
      load16(xs + (size_t)mc * D_DIM + k0 + skk, (char*)As + c * 1024);
      load16(W0 + (size_t)m * D_DIM + k0 + skk, (char*)B0s + c * 1024);
      load16(W1 + (size_t)m * D_DIM + k0 + skk, (char*)B1s + c * 1024);
    }
    __syncthreads();
#pragma unroll
    for (int ks = 0; ks < 64; ks += 32) {
      const int cb = (ks >> 3) + lq;
      s16x8 af[4], b0[4], b1[4];
#pragma unroll
      for (int t = 0; t < 4; t++) {
        af[t] = *(const s16x8*)&As[sw(wm + t * 16 + lm, cb)];
        b0[t] = *(const s16x8*)&B0s[sw(wn + t * 16 + lm, cb)];
        b1[t] = *(const s16x8*)&B1s[sw(wn + t * 16 + lm, cb)];
      }
#pragma unroll
      for (int im = 0; im < 4; im++)
#pragma unroll
        for (int in = 0; in < 4; in++) {
          acc0[im][in] = __builtin_amdgcn_mfma_f32_16x16x32_bf16(
              af[im], b0[in], acc0[im][in], 0, 0, 0);
          acc1[im][in] = __builtin_amdgcn_mfma_f32_16x16x32_bf16(
              af[im], b1[in], acc1[im][in], 0, 0, 0);
        }
    }
  }
#pragma unroll
  for (int im = 0; im < 4; im++) {
    int gmB = row0 + wm + im * 16 + lq * 4;
#pragma unroll
    for (int in = 0; in < 4; in++) {
      int gn = n0 + wn + in * 16 + lm;
#pragma unroll
      for (int r = 0; r < 4; r++) {
        int gm = gmB + r;
        if (gm < rowEnd) {
          float g = acc0[im][in][r];
          float s = g / (1.f + __expf(-g));
          h[(size_t)gm * F_DIM + gn] = bf_rn(s * acc1[im][in][r]);
        }
      }
    }
  }
}

// ---------------- GEMM2: h @ woT -> y (plain stores, 128x64 tiles) ----------------
__global__ __launch_bounds__(256, 4) void gemm2_kernel(
    const unsigned short* __restrict__ h, const unsigned short* __restrict__ woT,
    const int* __restrict__ tile_meta, float* __restrict__ y) {
  __shared__ unsigned short As[128 * 64];
  __shared__ unsigned short Bs[64 * 64];
  const int tile = blockIdx.x;
  if (tile >= tile_meta[0]) return;
  const int row0 = tile_meta[1 + 3 * tile];
  const int rowEnd = tile_meta[2 + 3 * tile];
  const int e = tile_meta[3 + 3 * tile];
  const int n0 = blockIdx.y * 64;
  const unsigned short* W = woT + ((size_t)e * D_DIM + n0) * F_DIM;

  const int tid = threadIdx.x;
  const int lane = tid & 63, wv = tid >> 6;
  const int wm = (wv & 1) * 64, wn = (wv >> 1) * 32;
  const int lm = lane & 15, lq = lane >> 4;
  const int srow = lane >> 3;
  const int skk = ((lane & 7) ^ srow) << 3;

  f32x4 acc[4][2];
#pragma unroll
  for (int i = 0; i < 4; i++)
#pragma unroll
    for (int j = 0; j < 2; j++) acc[i][j] = 0.f;

  for (int k0 = 0; k0 < F_DIM; k0 += 64) {
    __syncthreads();
#pragma unroll
    for (int r = 0; r < 4; r++) {
      const int c = r * 4 + wv;
      const int m = c * 8 + srow;
      int mc = row0 + m; if (mc > ROWS - 1) mc = ROWS - 1;
      load16(h + (size_t)mc * F_DIM + k0 + skk, (char*)As + c * 1024);
    }
#pragma unroll
    for (int r = 0; r < 2; r++) {
      const int c = r * 4 + wv;
      const int m = c * 8 + srow;
      load16(W + (size_t)m * F_DIM + k0 + skk, (char*)Bs + c * 1024);
    }
    __syncthreads();
#pragma unroll
    for (int ks = 0; ks < 64; ks += 32) {
      const int cb = (ks >> 3) + lq;
      s16x8 af[4], bf[2];
#pragma unroll
      for (int t = 0; t < 4; t++)
        af[t] = *(const s16x8*)&As[sw(wm + t * 16 + lm, cb)];
#pragma unroll
      for (int t = 0; t < 2; t++)
        bf[t] = *(const s16x8*)&Bs[sw(wn + t * 16 + lm, cb)];
#pragma unroll
      for (int im = 0; im < 4; im++)
#pragma unroll
        for (int in = 0; in < 2; in++)
          acc[im][in] = __builtin_amdgcn_mfma_f32_16x16x32_bf16(
              af[im], bf[in], acc[im][in], 0, 0, 0);
    }
  }
#pragma unroll
  for (int im = 0; im < 4; im++) {
    int gmB = row0 + wm + im * 16 + lq * 4;
#pragma unroll
    for (int in = 0; in < 2; in++) {
      int gn = n0 + wn + in * 16 + lm;
#pragma unroll
      for (int r = 0; r < 4; r++) {
        int gm = gmB + r;
        if (gm < rowEnd) y[(size_t)gm * D_DIM + gn] = acc[im][in][r];
      }
    }
  }
}

// ---------------- combine: out[t] = tw0*y[unsort[2t]] + tw1*y[unsort[2t+1]] ----
__global__ __launch_bounds__(256) void combine_kernel(const float* __restrict__ y,
                                                      const float* __restrict__ tw,
                                                      const int* __restrict__ unsort,
                                                      float* __restrict__ out) {
  const int tkn = blockIdx.x;
  const int r0 = unsort[2 * tkn], r1 = unsort[2 * tkn + 1];
  const float w0 = tw[2 * tkn], w1 = tw[2 * tkn + 1];
  const int c = threadIdx.x * 4;
  float4 a = *(const float4*)(y + (size_t)r0 * D_DIM + c);
  float4 b = *(const float4*)(y + (size_t)r1 * D_DIM + c);
  float4 o = {w0 * a.x + w1 * b.x, w0 * a.y + w1 * b.y,
              w0 * a.z + w1 * b.z, w0 * a.w + w1 * b.w};
  *(float4*)(out + (size_t)tkn * D_DIM + c) = o;
}

// ================= fallback (round-0) kernels, small-ws path =================
__device__ __forceinline__ void stage_bt(const float* __restrict__ Wt, int ldw,
                                         unsigned short* Bs, int tid) {
#pragma unroll
  for (int it = 0; it < 4; it++) {
    const int kp = (tid & 7) + it * 8;
    const int nq = tid >> 3;
    const float* p = Wt + (size_t)(2 * kp) * ldw + nq * 4;
    const float4 va = *(const float4*)p;
    const float4 vb = *(const float4*)(p + ldw);
    unsigned short* b = Bs + (nq * 4) * LDK + 2 * kp;
    *(unsigned*)(b)           = pack_trunc(va.x, vb.x);
    *(unsigned*)(b + LDK)     = pack_trunc(va.y, vb.y);
    *(unsigned*)(b + 2 * LDK) = pack_trunc(va.z, vb.z);
    *(unsigned*)(b + 3 * LDK) = pack_trunc(va.w, vb.w);
  }
}

__global__ __launch_bounds__(256, 2) void gemm1_fb(
    const float* __restrict__ x, const float* __restrict__ wi0,
    const float* __restrict__ wi1, const int* __restrict__ sorted_flat,
    const int* __restrict__ tile_meta, unsigned short* __restrict__ h) {
  __shared__ unsigned short As[128 * LDK];
  __shared__ unsigned short B0s[128 * LDK];
  __shared__ unsigned short B1s[128 * LDK];
  __shared__ int tok[128];
  const int tile = blockIdx.x;
  if (tile >= tile_meta[0]) return;
  const int row0 = tile_meta[1 + 3 * tile];
  const int rowEnd = tile_meta[2 + 3 * tile];
  const int e = tile_meta[3 + 3 * tile];
  const int n0 = blockIdx.y * 128;
  const float* W0 = wi0 + (size_t)e * D_DIM * F_DIM;
  const float* W1 = wi1 + (size_t)e * D_DIM * F_DIM;
  const int tid = threadIdx.x;
  if (tid < 128) {
    int r = row0 + tid; if (r > ROWS - 1) r = ROWS - 1;
    tok[tid] = sorted_flat[r] >> 1;
  }
  f32x4 acc0[4][4], acc1[4][4];
#pragma unroll
  for (int i = 0; i < 4; i++)
#pragma unroll
    for (int j = 0; j < 4; j++) { acc0[i][j] = 0.f; acc1[i][j] = 0.f; }
  const int lane = tid & 63, wv = tid >> 6;
  const int wm = (wv & 1) * 64, wn = (wv >> 1) * 64;
  const int lm = lane & 15, lq = lane >> 4;
  for (int k0 = 0; k0 < D_DIM; k0 += 64) {
    __syncthreads();
#pragma unroll
    for (int i = 0; i < 8; i++) {
      int idx = tid + i * 256;
      int m = idx >> 4, kq = idx & 15;
      float4 v = *(const float4*)(x + (size_t)tok[m] * D_DIM + k0 + kq * 4);
      *(uint2*)&As[m * LDK + kq * 4] =
          make_uint2(pack_trunc(v.x, v.y), pack_trunc(v.z, v.w));
    }
    stage_bt(W0 + (size_t)k0 * F_DIM + n0, F_DIM, B0s, tid);
    stage_bt(W1 + (size_t)k0 * F_DIM + n0, F_DIM, B1s, tid);
    __syncthreads();
#pragma unroll
    for (int ks = 0; ks < 64; ks += 32) {
      s16x8 af[4], b0[4], b1[4];
#pragma unroll
      for (int t = 0; t < 4; t++) {
        af[t] = *(const s16x8*)&As[(wm + t * 16 + lm) * LDK + ks + lq * 8];
        b0[t] = *(const s16x8*)&B0s[(wn + t * 16 + lm) * LDK + ks + lq * 8];
        b1[t] = *(const s16x8*)&B1s[(wn + t * 16 + lm) * LDK + ks + lq * 8];
      }
#pragma unroll
      for (int im = 0; im < 4; im++)
#pragma unroll
        for (int in = 0; in < 4; in++) {
          acc0[im][in] = __builtin_amdgcn_mfma_f32_16x16x32_bf16(
              af[im], b0[in], acc0[im][in], 0, 0, 0);
          acc1[im][in] = __builtin_amdgcn_mfma_f32_16x16x32_bf16(
              af[im], b1[in], acc1[im][in], 0, 0, 0);
        }
    }
  }
#pragma unroll
  for (int im = 0; im < 4; im++) {
    int gmB = row0 + wm + im * 16 + lq * 4;
#pragma unroll
    for (int in = 0; in < 4; in++) {
      int gn = n0 + wn + in * 16 + lm;
#pragma unroll
      for (int r = 0; r < 4; r++) {
        int gm = gmB + r;
        if (gm < rowEnd) {
          float g = acc0[im][in][r];
          float s = g / (1.f + __expf(-g));
          h[(size_t)gm * F_DIM + gn] = bf_rn(s * acc1[im][in][r]);
        }
      }
    }
  }
}

__global__ __launch_bounds__(256, 3) void gemm2_fb(
    const unsigned short* __restrict__ h, const float* __restrict__ wo,
    const float* __restrict__ tw, const int* __restrict__ sorted_flat,
    const int* __restrict__ tile_meta, float* __restrict__ out) {
  __shared__ unsigned short As[128 * LDK];
  __shared__ unsigned short Bs[128 * LDK];
  __shared__ int sTok[128];
  __shared__ float sWgt[128];
  const int tile = blockIdx.x;
  if (tile >= tile_meta[0]) return;
  const int row0 = tile_meta[1 + 3 * tile];
  const int rowEnd = tile_meta[2 + 3 * tile];
  const int e = tile_meta[3 + 3 * tile];
  const int n0 = blockIdx.y * 128;
  const float* W = wo + (size_t)e * F_DIM * D_DIM;
  const int tid = threadIdx.x;
  if (tid < 128) {
    int r = row0 + tid; if (r > ROWS - 1) r = ROWS - 1;
    int fl = sorted_flat[r];
    sTok[tid] = fl >> 1;
    sWgt[tid] = tw[fl];
  }
  f32x4 acc[4][4];
#pragma unroll
  for (int i = 0; i < 4; i++)
#pragma unroll
    for (int j = 0; j < 4; j++) acc[i][j] = 0.f;
  const int lane = tid & 63, wv = tid >> 6;
  const int wm = (wv & 1) * 64, wn = (wv >> 1) * 64;
  const int lm = lane & 15, lq = lane >> 4;
  for (int k0 = 0; k0 < F_DIM; k0 += 64) {
    __syncthreads();
#pragma unroll
    for (int i = 0; i < 8; i++) {
      int idx = tid + i * 256;
      int m = idx >> 4, kq = idx & 15;
      int gm = row0 + m; if (gm > ROWS - 1) gm = ROWS - 1;
      *(uint2*)&As[m * LDK + kq * 4] =
          *(const uint2*)(h + (size_t)gm * F_DIM + k0 + kq * 4);
    }
    stage_bt(W + (size_t)k0 * D_DIM + n0, D_DIM, Bs, tid);
    __syncthreads();
#pragma unroll
    for (int ks = 0; ks < 64; ks += 32) {
      s16x8 af[4], bf[4];
#pragma unroll
      for (int t = 0; t < 4; t++) {
        af[t] = *(const s16x8*)&As[(wm + t * 16 + lm) * LDK + ks + lq * 8];
        bf[t] = *(const s16x8*)&Bs[(wn + t * 16 + lm) * LDK + ks + lq * 8];
      }
#pragma unroll
      for (int im = 0; im < 4; im++)
#pragma unroll
        for (int in = 0; in < 4; in++)
          acc[im][in] = __builtin_amdgcn_mfma_f32_16x16x32_bf16(
              af[im], bf[in], acc[im][in], 0, 0, 0);
    }
  }
#pragma unroll
  for (int im = 0; im < 4; im++) {
    int lrB = wm + im * 16 + lq * 4;
#pragma unroll
    for (int in = 0; in < 4; in++) {
      int gn = n0 + wn + in * 16 + lm;
#pragma unroll
      for (int r = 0; r < 4; r++) {
        int lr = lrB + r;
        int gm = row0 + lr;
        if (gm < rowEnd)
          atomicAdd(out + (size_t)sTok[lr] * D_DIM + gn, sWgt[lr] * acc[im][in][r]);
      }
    }
  }
}

extern "C" void kernel_launch(void* const* d_in, const int* in_sizes, int n_in,
                              void* d_out, int out_size, void* d_ws, size_t ws_size,
                              hipStream_t stream) {
  const float* x   = (const float*)d_in[0];
  const float* tw  = (const float*)d_in[1];
  const int*   ids = (const int*)d_in[2];
  const float* wi0 = (const float*)d_in[3];
  const float* wi1 = (const float*)d_in[4];
  const float* wo  = (const float*)d_in[5];
  float* out = (float*)d_out;

  int* tile_meta = (int*)d_ws;            // 256 ints
  int* sorted_flat = tile_meta + 256;     // 4096 ints
  int* unsort = sorted_flat + ROWS;       // 4096 ints (ends < 64KB)

  const size_t MB = 1024 * 1024;
  const size_t XS_OFF = 64 * 1024;
  const size_t H_OFF  = XS_OFF + 8 * MB;
  const size_t W0_OFF = H_OFF + 16 * MB;   // y (16MB fp32) reuses this after gemm1
  const size_t W1_OFF = W0_OFF + 32 * MB;
  const size_t WO_OFF = W1_OFF + 32 * MB;
  const size_t NEED   = WO_OFF + 32 * MB;  // ~120.06 MB

  route_kernel<<<1, 512, 0, stream>>>(ids, sorted_flat, unsort, tile_meta);
  if (ws_size >= NEED) {
    unsigned short* xs  = (unsigned short*)((char*)d_ws + XS_OFF);
    unsigned short* h   = (unsigned short*)((char*)d_ws + H_OFF);
    unsigned short* w0T = (unsigned short*)((char*)d_ws + W0_OFF);
    unsigned short* w1T = (unsigned short*)((char*)d_ws + W1_OFF);
    unsigned short* woT = (unsigned short*)((char*)d_ws + WO_OFF);
    float* y = (float*)((char*)d_ws + W0_OFF);   // w0T dead after gemm1

    convT_lds<<<dim3(512, 24), 256, 0, stream>>>(wi0, wi1, wo, w0T, w1T, woT);
    gather_kernel<<<ROWS, 256, 0, stream>>>(x, sorted_flat, xs);
    gemm1_kernel<<<dim3(MAXTILE, F_DIM / 128), 256, 0, stream>>>(xs, w0T, w1T,
                                                                 tile_meta, h);
    gemm2_kernel<<<dim3(MAXTILE, D_DIM / 64), 256, 0, stream>>>(h, woT,
                                                                tile_meta, y);
    combine_kernel<<<ROWS / 2, 256, 0, stream>>>(y, tw, unsort, out);
  } else {
    unsigned short* h = (unsigned short*)((char*)d_ws + XS_OFF);
    zero_kernel<<<(out_size / 4 + 255) / 256, 256, 0, stream>>>((float4*)out,
                                                                out_size / 4);
    gemm1_fb<<<dim3(MAXTILE, F_DIM / 128), 256, 0, stream>>>(x, wi0, wi1,
                                                             sorted_flat,
                                                             tile_meta, h);
    gemm2_fb<<<dim3(MAXTILE, D_DIM / 128), 256, 0, stream>>>(h, wo, tw,
                                                             sorted_flat,
                                                             tile_meta, out);
  }
}

// Round 5
// 324.550 us; speedup vs baseline: 1.5258x; 1.0552x over previous
//
#include <hip/hip_runtime.h>
#include <hip/hip_bf16.h>

// EPMoE: E=8, K=2, D=1024, F=2048, T=2048, ROWS=4096.
// Fast path: route (LDS-staged ids) -> convT (fp32 W -> bf16 W^T, 128x64
// tiles, 8 loads in flight) -> gather -> gemm1 (128x64 tiles, (256,3),
// global_load_lds + XOR swizzle, SwiGLU) -> gemm2 (128x64, (256,4)) ->
// combine. gemm1/2 accumulators: 64/32 AGPR — fits waves-per-EU budget
// (R3 lesson: 128 AGPR + 120 VGPR at w=3 spilled -> 391MB scratch traffic).
// LDS swizzle: [R][64] bf16 rows = 128B = 32 banks; physical 16B chunk j of
// row m holds logical chunk j^(m&7) (applied on global source address;
// global_load_lds dst stays lane-contiguous).

#define D_DIM 1024
#define F_DIM 2048
#define ROWS 4096
#define MAXTILE 40
#define LDK 72   // fallback-path LDS k-stride

using f32x4 = __attribute__((ext_vector_type(4))) float;
using s16x8 = __attribute__((ext_vector_type(8))) short;

__device__ __forceinline__ unsigned pack_trunc(float lo, float hi) {
  return (__float_as_uint(lo) >> 16) | (__float_as_uint(hi) & 0xffff0000u);
}
__device__ __forceinline__ unsigned short bf_rn(float f) {
  unsigned u = __float_as_uint(f);
  u += 0x7fffu + ((u >> 16) & 1u);
  return (unsigned short)(u >> 16);
}
__device__ __forceinline__ unsigned pack_rn(float lo, float hi) {
  return (unsigned)bf_rn(lo) | ((unsigned)bf_rn(hi) << 16);
}

typedef const __attribute__((address_space(1))) void* gp_t;
typedef __attribute__((address_space(3))) void* lp_t;
__device__ __forceinline__ void load16(const void* g, void* l) {
  __builtin_amdgcn_global_load_lds((gp_t)g, (lp_t)l, 16, 0, 0);
}

// -------- routing: stable counting sort by expert (ids staged in LDS) --------
__global__ __launch_bounds__(512) void route_kernel(const int* __restrict__ ids,
                                                    int* __restrict__ sorted_flat,
                                                    int* __restrict__ unsort,
                                                    int* __restrict__ tile_meta) {
  __shared__ int sid[ROWS];
  __shared__ int cnt[8];
  __shared__ int off[9];
  const int tid = threadIdx.x;
#pragma unroll
  for (int j = 0; j < 2; j++) {
    int idx = tid + j * 512;                    // int4 index
    *(int4*)&sid[idx * 4] = *(const int4*)&ids[idx * 4];
  }
  __syncthreads();
  const int w = tid >> 6, lane = tid & 63;
  int c = 0;
  for (int base = 0; base < ROWS; base += 64)
    c += __popcll(__ballot(sid[base + lane] == w));
  if (lane == 0) cnt[w] = c;
  __syncthreads();
  if (tid == 0) {
    int o = 0;
    for (int e = 0; e < 8; e++) { off[e] = o; o += cnt[e]; }
    off[8] = o;
    int nT = 0;
    for (int e = 0; e < 8; e++) {
      for (int r0 = off[e]; r0 < off[e + 1]; r0 += 128) {
        tile_meta[1 + 3 * nT] = r0;
        tile_meta[2 + 3 * nT] = off[e + 1];
        tile_meta[3 + 3 * nT] = e;
        nT++;
      }
    }
    tile_meta[0] = nT;
  }
  __syncthreads();
  int pos = off[w];
  const unsigned long long below = (1ull << lane) - 1ull;
  for (int base = 0; base < ROWS; base += 64) {
    unsigned long long m = __ballot(sid[base + lane] == w);
    if (sid[base + lane] == w) {
      int p = pos + __popcll(m & below);
      sorted_flat[p] = base + lane;
      unsort[base + lane] = p;
    }
    pos += __popcll(m);
  }
}

__global__ void zero_kernel(float4* __restrict__ p, int n4) {
  int i = blockIdx.x * blockDim.x + threadIdx.x;
  if (i < n4) p[i] = float4{0.f, 0.f, 0.f, 0.f};
}

// ------- convT: 3 weight tensors fp32 [E][Kd][Nd] -> bf16 [E][Nd][Kd] -------
// 128(k) x 64(n) tile per block: 8 independent float4 loads up front (2x MLP
// of R4), VALU k-pair packing, LDS [64 n][65 uints] (2-way conflicts = free),
// 256B-contiguous per-row writes. 6144 blocks.
__global__ __launch_bounds__(256) void convT_lds(
    const float* __restrict__ wi0, const float* __restrict__ wi1,
    const float* __restrict__ wo, unsigned short* __restrict__ w0T,
    unsigned short* __restrict__ w1T, unsigned short* __restrict__ woT) {
  __shared__ unsigned t[64 * 65];  // [n][kpair]
  const int z = blockIdx.y;        // 0..23
  const int which = z >> 3, e = z & 7;
  const float* S;
  unsigned short* Dp;
  int Kd, Nd, nbits;
  if (which == 0)      { S = wi0; Dp = w0T; Kd = D_DIM; Nd = F_DIM; nbits = 5; }
  else if (which == 1) { S = wi1; Dp = w1T; Kd = D_DIM; Nd = F_DIM; nbits = 5; }
  else                 { S = wo;  Dp = woT; Kd = F_DIM; Nd = D_DIM; nbits = 4; }
  S  += (size_t)e * Kd * Nd;
  Dp += (size_t)e * Kd * Nd;
  const int n0 = (blockIdx.x & ((1 << nbits) - 1)) * 64;
  const int k0 = (blockIdx.x >> nbits) * 128;
  const int tid = threadIdx.x;
  const int nb = (tid & 15) * 4;
  // load all 8 float4 first (independent -> in flight together)
  float4 v[4][2];
#pragma unroll
  for (int i = 0; i < 4; i++) {
    const int kp = (tid >> 4) + i * 16;  // k-pair 0..63
    const float* p = S + (size_t)(k0 + 2 * kp) * Nd + n0 + nb;
    v[i][0] = *(const float4*)p;
    v[i][1] = *(const float4*)(p + Nd);
  }
#pragma unroll
  for (int i = 0; i < 4; i++) {
    const int kp = (tid >> 4) + i * 16;
    t[(nb + 0) * 65 + kp] = pack_rn(v[i][0].x, v[i][1].x);
    t[(nb + 1) * 65 + kp] = pack_rn(v[i][0].y, v[i][1].y);
    t[(nb + 2) * 65 + kp] = pack_rn(v[i][0].z, v[i][1].z);
    t[(nb + 3) * 65 + kp] = pack_rn(v[i][0].w, v[i][1].w);
  }
  __syncthreads();
  const int c = tid & 15;              // 16B chunk within 256B row
#pragma unroll
  for (int j = 0; j < 4; j++) {
    const int n = (tid >> 4) + j * 16;
    const unsigned* q = &t[n * 65 + c * 4];
    uint4 o = make_uint4(q[0], q[1], q[2], q[3]);
    *(uint4*)(Dp + (size_t)(n0 + n) * Kd + k0 + c * 8) = o;
  }
}

// ---------------- gather: x fp32 -> x_sorted bf16 ----------------
__global__ __launch_bounds__(256) void gather_kernel(const float* __restrict__ x,
                                                     const int* __restrict__ sorted_flat,
                                                     unsigned short* __restrict__ xs) {
  const int r = blockIdx.x;
  const int tok = sorted_flat[r] >> 1;
  const float4 v = *(const float4*)(x + (size_t)tok * D_DIM + threadIdx.x * 4);
  *(uint2*)(xs + (size_t)r * D_DIM + threadIdx.x * 4) =
      make_uint2(pack_rn(v.x, v.y), pack_rn(v.z, v.w));
}

// swizzled frag address: physical chunk = logical_chunk ^ (row&7)
__device__ __forceinline__ int sw(int row, int chunk) {
  return row * 64 + ((chunk ^ (row & 7)) << 3);
}

// ------- GEMM1: xs @ (w0T,w1T) -> h = silu(g0)*g1.  128(m) x 64(n) tiles -------
__global__ __launch_bounds__(256, 3) void gemm1_kernel(
    const unsigned short* __restrict__ xs, const unsigned short* __restrict__ w0T,
    const unsigned short* __restrict__ w1T, const int* __restrict__ tile_meta,
    unsigned short* __restrict__ h) {
  __shared__ unsigned short As[128 * 64];
  __shared__ unsigned short B0s[64 * 64];
  __shared__ unsigned short B1s[64 * 64];
  const int tile = blockIdx.x;
  if (tile >= tile_meta[0]) return;
  const int row0 = tile_meta[1 + 3 * tile];
  const int rowEnd = tile_meta[2 + 3 * tile];
  const int e = tile_meta[3 + 3 * tile];
  const int n0 = blockIdx.y * 64;
  const unsigned short* W0 = w0T + ((size_t)e * F_DIM + n0) * D_DIM;
  const unsigned short* W1 = w1T + ((size_t)e * F_DIM + n0) * D_DIM;

  const int tid = threadIdx.x;
  const int lane = tid & 63, wv = tid >> 6;
  const int wm = (wv & 1) * 64, wn = (wv >> 1) * 32;
  const int lm = lane & 15, lq = lane >> 4;
  const int srow = lane >> 3;                       // staging row-in-chunk
  const int skk = ((lane & 7) ^ srow) << 3;         // swizzled source elem off

  f32x4 acc0[4][2], acc1[4][2];
#pragma unroll
  for (int i = 0; i < 4; i++)
#pragma unroll
    for (int j = 0; j < 2; j++) { acc0[i][j] = 0.f; acc1[i][j] = 0.f; }

  for (int k0 = 0; k0 < D_DIM; k0 += 64) {
    __syncthreads();
#pragma unroll
    for (int r = 0; r < 4; r++) {                 // A: 16 chunks, 4/wave
      const int c = r * 4 + wv;
      const int m = c * 8 + srow;
      int mc = row0 + m; if (mc > ROWS - 1) mc = ROWS - 1;
      load16(xs + (size_t)mc * D_DIM + k0 + skk, (char*)As + c * 1024);
    }
#pragma unroll
    for (int r = 0; r < 2; r++) {                 // B0,B1: 8 chunks, 2/wave
      const int c = r * 4 + wv;
      const int m = c * 8 + srow;
      load16(W0 + (size_t)m * D_DIM + k0 + skk, (char*)B0s + c * 1024);
      load16(W1 + (size_t)m * D_DIM + k0 + skk, (char*)B1s + c * 1024);
    }
    __syncthreads();
#pragma unroll
    for (int ks = 0; ks < 64; ks += 32) {
      const int cb = (ks >> 3) + lq;
      s16x8 af[4], b0[2], b1[2];
#pragma unroll
      for (int t = 0; t < 4; t++)
        af[t] = *(const s16x8*)&As[sw(wm + t * 16 + lm, cb)];
#pragma unroll
      for (int t = 0; t < 2; t++) {
        b0[t] = *(const s16x8*)&B0s[sw(wn + t * 16 + lm, cb)];
        b1[t] = *(const s16x8*)&B1s[sw(wn + t * 16 + lm, cb)];
      }
#pragma unroll
      for (int im = 0; im < 4; im++)
#pragma unroll
        for (int in = 0; in < 2; in++) {
          acc0[im][in] = __builtin_amdgcn_mfma_f32_16x16x32_bf16(
              af[im], b0[in], acc0[im][in], 0, 0, 0);
          acc1[im][in] = __builtin_amdgcn_mfma_f32_16x16x32_bf16(
              af[im], b1[in], acc1[im][in], 0, 0, 0);
        }
    }
  }
#pragma unroll
  for (int im = 0; im < 4; im++) {
    int gmB = row0 + wm + im * 16 + lq * 4;
#pragma unroll
    for (int in = 0; in < 2; in++) {
      int gn = n0 + wn + in * 16 + lm;
#pragma unroll
      for (int r = 0; r < 4; r++) {
        int gm = gmB + r;
        if (gm < rowEnd) {
          float g = acc0[im][in][r];
          float s = g / (1.f + __expf(-g));
          h[(size_t)gm * F_DIM + gn] = bf_rn(s * acc1[im][in][r]);
        }
      }
    }
  }
}

// ---------------- GEMM2: h @ woT -> y (plain stores, 128x64 tiles) ----------------
__global__ __launch_bounds__(256, 4) void gemm2_kernel(
    const unsigned short* __restrict__ h, const unsigned short* __restrict__ woT,
    const int* __restrict__ tile_meta, float* __restrict__ y) {
  __shared__ unsigned short As[128 * 64];
  __shared__ unsigned short Bs[64 * 64];
  const int tile = blockIdx.x;
  if (tile >= tile_meta[0]) return;
  const int row0 = tile_meta[1 + 3 * tile];
  const int rowEnd = tile_meta[2 + 3 * tile];
  const int e = tile_meta[3 + 3 * tile];
  const int n0 = blockIdx.y * 64;
  const unsigned short* W = woT + ((size_t)e * D_DIM + n0) * F_DIM;

  const int tid = threadIdx.x;
  const int lane = tid & 63, wv = tid >> 6;
  const int wm = (wv & 1) * 64, wn = (wv >> 1) * 32;
  const int lm = lane & 15, lq = lane >> 4;
  const int srow = lane >> 3;
  const int skk = ((lane & 7) ^ srow) << 3;

  f32x4 acc[4][2];
#pragma unroll
  for (int i = 0; i < 4; i++)
#pragma unroll
    for (int j = 0; j < 2; j++) acc[i][j] = 0.f;

  for (int k0 = 0; k0 < F_DIM; k0 += 64) {
    __syncthreads();
#pragma unroll
    for (int r = 0; r < 4; r++) {
      const int c = r * 4 + wv;
      const int m = c * 8 + srow;
      int mc = row0 + m; if (mc > ROWS - 1) mc = ROWS - 1;
      load16(h + (size_t)mc * F_DIM + k0 + skk, (char*)As + c * 1024);
    }
#pragma unroll
    for (int r = 0; r < 2; r++) {
      const int c = r * 4 + wv;
      const int m = c * 8 + srow;
      load16(W + (size_t)m * F_DIM + k0 + skk, (char*)Bs + c * 1024);
    }
    __syncthreads();
#pragma unroll
    for (int ks = 0; ks < 64; ks += 32) {
      const int cb = (ks >> 3) + lq;
      s16x8 af[4], bf[2];
#pragma unroll
      for (int t = 0; t < 4; t++)
        af[t] = *(const s16x8*)&As[sw(wm + t * 16 + lm, cb)];
#pragma unroll
      for (int t = 0; t < 2; t++)
        bf[t] = *(const s16x8*)&Bs[sw(wn + t * 16 + lm, cb)];
#pragma unroll
      for (int im = 0; im < 4; im++)
#pragma unroll
        for (int in = 0; in < 2; in++)
          acc[im][in] = __builtin_amdgcn_mfma_f32_16x16x32_bf16(
              af[im], bf[in], acc[im][in], 0, 0, 0);
    }
  }
#pragma unroll
  for (int im = 0; im < 4; im++) {
    int gmB = row0 + wm + im * 16 + lq * 4;
#pragma unroll
    for (int in = 0; in < 2; in++) {
      int gn = n0 + wn + in * 16 + lm;
#pragma unroll
      for (int r = 0; r < 4; r++) {
        int gm = gmB + r;
        if (gm < rowEnd) y[(size_t)gm * D_DIM + gn] = acc[im][in][r];
      }
    }
  }
}

// ---------------- combine: out[t] = tw0*y[unsort[2t]] + tw1*y[unsort[2t+1]] ----
__global__ __launch_bounds__(256) void combine_kernel(const float* __restrict__ y,
                                                      const float* __restrict__ tw,
                                                      const int* __restrict__ unsort,
                                                      float* __restrict__ out) {
  const int tkn = blockIdx.x;
  const int r0 = unsort[2 * tkn], r1 = unsort[2 * tkn + 1];
  const float w0 = tw[2 * tkn], w1 = tw[2 * tkn + 1];
  const int c = threadIdx.x * 4;
  float4 a = *(const float4*)(y + (size_t)r0 * D_DIM + c);
  float4 b = *(const float4*)(y + (size_t)r1 * D_DIM + c);
  float4 o = {w0 * a.x + w1 * b.x, w0 * a.y + w1 * b.y,
              w0 * a.z + w1 * b.z, w0 * a.w + w1 * b.w};
  *(float4*)(out + (size_t)tkn * D_DIM + c) = o;
}

// ================= fallback (round-0) kernels, small-ws path =================
__device__ __forceinline__ void stage_bt(const float* __restrict__ Wt, int ldw,
                                         unsigned short* Bs, int tid) {
#pragma unroll
  for (int it = 0; it < 4; it++) {
    const int kp = (tid & 7) + it * 8;
    const int nq = tid >> 3;
    const float* p = Wt + (size_t)(2 * kp) * ldw + nq * 4;
    const float4 va = *(const float4*)p;
    const float4 vb = *(const float4*)(p + ldw);
    unsigned short* b = Bs + (nq * 4) * LDK + 2 * kp;
    *(unsigned*)(b)           = pack_trunc(va.x, vb.x);
    *(unsigned*)(b + LDK)     = pack_trunc(va.y, vb.y);
    *(unsigned*)(b + 2 * LDK) = pack_trunc(va.z, vb.z);
    *(unsigned*)(b + 3 * LDK) = pack_trunc(va.w, vb.w);
  }
}

__global__ __launch_bounds__(256, 2) void gemm1_fb(
    const float* __restrict__ x, const float* __restrict__ wi0,
    const float* __restrict__ wi1, const int* __restrict__ sorted_flat,
    const int* __restrict__ tile_meta, unsigned short* __restrict__ h) {
  __shared__ unsigned short As[128 * LDK];
  __shared__ unsigned short B0s[128 * LDK];
  __shared__ unsigned short B1s[128 * LDK];
  __shared__ int tok[128];
  const int tile = blockIdx.x;
  if (tile >= tile_meta[0]) return;
  const int row0 = tile_meta[1 + 3 * tile];
  const int rowEnd = tile_meta[2 + 3 * tile];
  const int e = tile_meta[3 + 3 * tile];
  const int n0 = blockIdx.y * 128;
  const float* W0 = wi0 + (size_t)e * D_DIM * F_DIM;
  const float* W1 = wi1 + (size_t)e * D_DIM * F_DIM;
  const int tid = threadIdx.x;
  if (tid < 128) {
    int r = row0 + tid; if (r > ROWS - 1) r = ROWS - 1;
    tok[tid] = sorted_flat[r] >> 1;
  }
  f32x4 acc0[4][4], acc1[4][4];
#pragma unroll
  for (int i = 0; i < 4; i++)
#pragma unroll
    for (int j = 0; j < 4; j++) { acc0[i][j] = 0.f; acc1[i][j] = 0.f; }
  const int lane = tid & 63, wv = tid >> 6;
  const int wm = (wv & 1) * 64, wn = (wv >> 1) * 64;
  const int lm = lane & 15, lq = lane >> 4;
  for (int k0 = 0; k0 < D_DIM; k0 += 64) {
    __syncthreads();
#pragma unroll
    for (int i = 0; i < 8; i++) {
      int idx = tid + i * 256;
      int m = idx >> 4, kq = idx & 15;
      float4 v = *(const float4*)(x + (size_t)tok[m] * D_DIM + k0 + kq * 4);
      *(uint2*)&As[m * LDK + kq * 4] =
          make_uint2(pack_trunc(v.x, v.y), pack_trunc(v.z, v.w));
    }
    stage_bt(W0 + (size_t)k0 * F_DIM + n0, F_DIM, B0s, tid);
    stage_bt(W1 + (size_t)k0 * F_DIM + n0, F_DIM, B1s, tid);
    __syncthreads();
#pragma unroll
    for (int ks = 0; ks < 64; ks += 32) {
      s16x8 af[4], b0[4], b1[4];
#pragma unroll
      for (int t = 0; t < 4; t++) {
        af[t] = *(const s16x8*)&As[(wm + t * 16 + lm) * LDK + ks + lq * 8];
        b0[t] = *(const s16x8*)&B0s[(wn + t * 16 + lm) * LDK + ks + lq * 8];
        b1[t] = *(const s16x8*)&B1s[(wn + t * 16 + lm) * LDK + ks + lq * 8];
      }
#pragma unroll
      for (int im = 0; im < 4; im++)
#pragma unroll
        for (int in = 0; in < 4; in++) {
          acc0[im][in] = __builtin_amdgcn_mfma_f32_16x16x32_bf16(
              af[im], b0[in], acc0[im][in], 0, 0, 0);
          acc1[im][in] = __builtin_amdgcn_mfma_f32_16x16x32_bf16(
              af[im], b1[in], acc1[im][in], 0, 0, 0);
        }
    }
  }
#pragma unroll
  for (int im = 0; im < 4; im++) {
    int gmB = row0 + wm + im * 16 + lq * 4;
#pragma unroll
    for (int in = 0; in < 4; in++) {
      int gn = n0 + wn + in * 16 + lm;
#pragma unroll
      for (int r = 0; r < 4; r++) {
        int gm = gmB + r;
        if (gm < rowEnd) {
          float g = acc0[im][in][r];
          float s = g / (1.f + __expf(-g));
          h[(size_t)gm * F_DIM + gn] = bf_rn(s * acc1[im][in][r]);
        }
      }
    }
  }
}

__global__ __launch_bounds__(256, 3) void gemm2_fb(
    const unsigned short* __restrict__ h, const float* __restrict__ wo,
    const float* __restrict__ tw, const int* __restrict__ sorted_flat,
    const int* __restrict__ tile_meta, float* __restrict__ out) {
  __shared__ unsigned short As[128 * LDK];
  __shared__ unsigned short Bs[128 * LDK];
  __shared__ int sTok[128];
  __shared__ float sWgt[128];
  const int tile = blockIdx.x;
  if (tile >= tile_meta[0]) return;
  const int row0 = tile_meta[1 + 3 * tile];
  const int rowEnd = tile_meta[2 + 3 * tile];
  const int e = tile_meta[3 + 3 * tile];
  const int n0 = blockIdx.y * 128;
  const float* W = wo + (size_t)e * F_DIM * D_DIM;
  const int tid = threadIdx.x;
  if (tid < 128) {
    int r = row0 + tid; if (r > ROWS - 1) r = ROWS - 1;
    int fl = sorted_flat[r];
    sTok[tid] = fl >> 1;
    sWgt[tid] = tw[fl];
  }
  f32x4 acc[4][4];
#pragma unroll
  for (int i = 0; i < 4; i++)
#pragma unroll
    for (int j = 0; j < 4; j++) acc[i][j] = 0.f;
  const int lane = tid & 63, wv = tid >> 6;
  const int wm = (wv & 1) * 64, wn = (wv >> 1) * 64;
  const int lm = lane & 15, lq = lane >> 4;
  for (int k0 = 0; k0 < F_DIM; k0 += 64) {
    __syncthreads();
#pragma unroll
    for (int i = 0; i < 8; i++) {
      int idx = tid + i * 256;
      int m = idx >> 4, kq = idx & 15;
      int gm = row0 + m; if (gm > ROWS - 1) gm = ROWS - 1;
      *(uint2*)&As[m * LDK + kq * 4] =
          *(const uint2*)(h + (size_t)gm * F_DIM + k0 + kq * 4);
    }
    stage_bt(W + (size_t)k0 * D_DIM + n0, D_DIM, Bs, tid);
    __syncthreads();
#pragma unroll
    for (int ks = 0; ks < 64; ks += 32) {
      s16x8 af[4], bf[4];
#pragma unroll
      for (int t = 0; t < 4; t++) {
        af[t] = *(const s16x8*)&As[(wm + t * 16 + lm) * LDK + ks + lq * 8];
        bf[t] = *(const s16x8*)&Bs[(wn + t * 16 + lm) * LDK + ks + lq * 8];
      }
#pragma unroll
      for (int im = 0; im < 4; im++)
#pragma unroll
        for (int in = 0; in < 4; in++)
          acc[im][in] = __builtin_amdgcn_mfma_f32_16x16x32_bf16(
              af[im], bf[in], acc[im][in], 0, 0, 0);
    }
  }
#pragma unroll
  for (int im = 0; im < 4; im++) {
    int lrB = wm + im * 16 + lq * 4;
#pragma unroll
    for (int in = 0; in < 4; in++) {
      int gn = n0 + wn + in * 16 + lm;
#pragma unroll
      for (int r = 0; r < 4; r++) {
        int lr = lrB + r;
        int gm = row0 + lr;
        if (gm < rowEnd)
          atomicAdd(out + (size_t)sTok[lr] * D_DIM + gn, sWgt[lr] * acc[im][in][r]);
      }
    }
  }
}

extern "C" void kernel_launch(void* const* d_in, const int* in_sizes, int n_in,
                              void* d_out, int out_size, void* d_ws, size_t ws_size,
                              hipStream_t stream) {
  const float* x   = (const float*)d_in[0];
  const float* tw  = (const float*)d_in[1];
  const int*   ids = (const int*)d_in[2];
  const float* wi0 = (const float*)d_in[3];
  const float* wi1 = (const float*)d_in[4];
  const float* wo  = (const float*)d_in[5];
  float* out = (float*)d_out;

  int* tile_meta = (int*)d_ws;            // 256 ints
  int* sorted_flat = tile_meta + 256;     // 4096 ints
  int* unsort = sorted_flat + ROWS;       // 4096 ints (ends < 64KB)

  const size_t MB = 1024 * 1024;
  const size_t XS_OFF = 64 * 1024;
  const size_t H_OFF  = XS_OFF + 8 * MB;
  const size_t W0_OFF = H_OFF + 16 * MB;   // y (16MB fp32) reuses this after gemm1
  const size_t W1_OFF = W0_OFF + 32 * MB;
  const size_t WO_OFF = W1_OFF + 32 * MB;
  const size_t NEED   = WO_OFF + 32 * MB;  // ~120.06 MB

  route_kernel<<<1, 512, 0, stream>>>(ids, sorted_flat, unsort, tile_meta);
  if (ws_size >= NEED) {
    unsigned short* xs  = (unsigned short*)((char*)d_ws + XS_OFF);
    unsigned short* h   = (unsigned short*)((char*)d_ws + H_OFF);
    unsigned short* w0T = (unsigned short*)((char*)d_ws + W0_OFF);
    unsigned short* w1T = (unsigned short*)((char*)d_ws + W1_OFF);
    unsigned short* woT = (unsigned short*)((char*)d_ws + WO_OFF);
    float* y = (float*)((char*)d_ws + W0_OFF);   // w0T dead after gemm1

    convT_lds<<<dim3(256, 24), 256, 0, stream>>>(wi0, wi1, wo, w0T, w1T, woT);
    gather_kernel<<<ROWS, 256, 0, stream>>>(x, sorted_flat, xs);
    gemm1_kernel<<<dim3(MAXTILE, F_DIM / 64), 256, 0, stream>>>(xs, w0T, w1T,
                                                                tile_meta, h);
    gemm2_kernel<<<dim3(MAXTILE, D_DIM / 64), 256, 0, stream>>>(h, woT,
                                                                tile_meta, y);
    combine_kernel<<<ROWS / 2, 256, 0, stream>>>(y, tw, unsort, out);
  } else {
    unsigned short* h = (unsigned short*)((char*)d_ws + XS_OFF);
    zero_kernel<<<(out_size / 4 + 255) / 256, 256, 0, stream>>>((float4*)out,
                                                                out_size / 4);
    gemm1_fb<<<dim3(MAXTILE, F_DIM / 128), 256, 0, stream>>>(x, wi0, wi1,
                                                             sorted_flat,
                                                             tile_meta, h);
    gemm2_fb<<<dim3(MAXTILE, D_DIM / 128), 256, 0, stream>>>(h, wo, tw,
                                                             sorted_flat,
                                                             tile_meta, out);
  }
}